// Round 11
// baseline (208.428 us; speedup 1.0000x reference)
//
#include <hip/hip_runtime.h>
#include <hip/hip_fp16.h>

typedef unsigned short u16;
using f32x4 = __attribute__((ext_vector_type(4))) float;
using half8 = __attribute__((ext_vector_type(8))) _Float16;
using us8   = __attribute__((ext_vector_type(8))) unsigned short;
using us4   = __attribute__((ext_vector_type(4))) unsigned short;

#define N_PTS 8192
#define D_DIM 768
#define TOPK  21
#define KSTEPS 12
#define CAPL  8          // R6-proven: lambda=2.6/tile-side, spills ~0
#define CAPG  448

// ---------------- async global->LDS (16B per lane) ----------------
__device__ __forceinline__ void gload16(const void* g, void* l) {
    __builtin_amdgcn_global_load_lds(
        (const __attribute__((address_space(1))) void*)g,
        (__attribute__((address_space(3))) void*)l,
        16, 0, 0);
}

// ---------------- wave (64-lane) reductions ----------------
__device__ __forceinline__ int wred_sum_i(int c) {
#pragma unroll
    for (int o = 32; o >= 1; o >>= 1) c += __shfl_xor(c, o, 64);
    return c;
}
__device__ __forceinline__ float wred_sum_f(float c) {
#pragma unroll
    for (int o = 32; o >= 1; o >>= 1) c += __shfl_xor(c, o, 64);
    return c;
}
__device__ __forceinline__ float wred_min_f(float c) {
#pragma unroll
    for (int o = 32; o >= 1; o >>= 1) c = fminf(c, __shfl_xor(c, o, 64));
    return c;
}

// ---------------- kernel 1: fp32 -> fp16 + row norms (vectorized) ----
__global__ __launch_bounds__(256) void prep_kernel(const float* __restrict__ X,
                                                   u16* __restrict__ Xh,
                                                   float* __restrict__ norms,
                                                   int* __restrict__ cnt_g) {
    const int tid  = threadIdx.x;
    const int lane = tid & 63;
    const int row  = blockIdx.x * 4 + (tid >> 6);
    const float4* xr = (const float4*)(X + (size_t)row * D_DIM);
    us4* hr = (us4*)(Xh + (size_t)row * D_DIM);
    float s = 0.f;
#pragma unroll
    for (int j = 0; j < 3; ++j) {
        const float4 v = xr[lane + j * 64];
        _Float16 h0 = (_Float16)v.x, h1 = (_Float16)v.y,
                 h2 = (_Float16)v.z, h3 = (_Float16)v.w;
        us4 u;
        u[0] = __builtin_bit_cast(u16, h0);
        u[1] = __builtin_bit_cast(u16, h1);
        u[2] = __builtin_bit_cast(u16, h2);
        u[3] = __builtin_bit_cast(u16, h3);
        hr[lane + j * 64] = u;
        const float f0 = (float)h0, f1 = (float)h1, f2 = (float)h2, f3 = (float)h3;
        s += f0 * f0 + f1 * f1 + f2 * f2 + f3 * f3;
    }
#pragma unroll
    for (int o = 32; o >= 1; o >>= 1) s += __shfl_down(s, o, 64);
    if (lane == 0) {
        norms[row] = s;
        cnt_g[row] = 0;
    }
}

// ---------------- kernel 2: sample GEMM (cols 0..1023) -> d2 as fp16 ----
__global__ __launch_bounds__(256, 4) void gemm_tau_kernel(const u16* __restrict__ Xh,
                                                          const float* __restrict__ norms,
                                                          u16* __restrict__ d2h) {
    __shared__ __align__(16) u16 As[128 * 64];
    __shared__ __align__(16) u16 Bs[128 * 64];
    __shared__ float nAs[128];
    __shared__ float nBs[128];

    const int tid  = threadIdx.x;
    const int lane = tid & 63;
    const int wid  = tid >> 6;
    const int wr   = wid >> 1;
    const int wc   = wid & 1;
    const int l16  = lane >> 4;
    const int l15  = lane & 15;

    const int bid = blockIdx.x;
    const int swz = (bid & 7) * 64 + (bid >> 3);
    const int rowTile = swz >> 3;
    const int chunk   = swz & 7;
    const int r0 = rowTile * 128;
    const int cb = chunk * 128;

    if (tid < 128) {
        nAs[tid] = norms[r0 + tid];
        nBs[tid] = norms[cb + tid];
    }

    const int rb   = tid >> 3;
    const int cole = (tid & 7) * 8;
    const int lofs = tid * 8;

    f32x4 acc[4][4];
#pragma unroll
    for (int m = 0; m < 4; ++m)
#pragma unroll
        for (int n = 0; n < 4; ++n) {
            f32x4 z = {0.f, 0.f, 0.f, 0.f};
            acc[m][n] = z;
        }

    for (int ks = 0; ks < KSTEPS; ++ks) {
        const int kofs = ks * 64;
#pragma unroll
        for (int i = 0; i < 4; ++i) {
            const int r = i * 32 + rb;
            gload16(Xh + (size_t)(r0 + r) * D_DIM + kofs + cole, &As[i * 2048 + lofs]);
            gload16(Xh + (size_t)(cb + r) * D_DIM + kofs + cole, &Bs[i * 2048 + lofs]);
        }
        __syncthreads();
#pragma unroll
        for (int kk = 0; kk < 2; ++kk) {
            const int ko = kk * 32 + l16 * 8;
            half8 af[4], bf[4];
#pragma unroll
            for (int m = 0; m < 4; ++m)
                af[m] = *reinterpret_cast<const half8*>(&As[(wr * 64 + m * 16 + l15) * 64 + ko]);
#pragma unroll
            for (int n = 0; n < 4; ++n)
                bf[n] = *reinterpret_cast<const half8*>(&Bs[(wc * 64 + n * 16 + l15) * 64 + ko]);
#pragma unroll
            for (int m = 0; m < 4; ++m)
#pragma unroll
                for (int n = 0; n < 4; ++n)
                    acc[m][n] = __builtin_amdgcn_mfma_f32_16x16x32_f16(af[m], bf[n], acc[m][n], 0, 0, 0);
        }
        __syncthreads();
    }

    float nAr[4][4], nBc[4];
#pragma unroll
    for (int m = 0; m < 4; ++m)
#pragma unroll
        for (int r = 0; r < 4; ++r) nAr[m][r] = nAs[wr * 64 + m * 16 + l16 * 4 + r];
#pragma unroll
    for (int n = 0; n < 4; ++n) nBc[n] = nBs[wc * 64 + n * 16 + l15];

#pragma unroll
    for (int m = 0; m < 4; ++m)
#pragma unroll
        for (int n = 0; n < 4; ++n)
#pragma unroll
            for (int r = 0; r < 4; ++r) {
                const int ri = r0 + wr * 64 + m * 16 + l16 * 4 + r;
                const int ci = cb + wc * 64 + n * 16 + l15;
                float d2 = fmaxf(nAr[m][r] + nBc[n] - 2.0f * acc[m][n][r], 0.0f);
                _Float16 h = (_Float16)d2;
                d2h[(size_t)ri * 1024 + ci] = __builtin_bit_cast(u16, h);
            }
}

// ---------------- kernel 3: per-row 21st-smallest of sample (bit search) ----
__global__ __launch_bounds__(256) void tau_select_kernel(const u16* __restrict__ d2h,
                                                         float* __restrict__ tauB) {
    const int tid  = threadIdx.x;
    const int lane = tid & 63;
    const int row  = blockIdx.x * 4 + (tid >> 6);

    const us8* p = (const us8*)(d2h + (size_t)row * 1024);
    us8 v0 = p[lane * 2];
    us8 v1 = p[lane * 2 + 1];

    unsigned lo = 0, hi = 0x7BFF;
#pragma unroll
    for (int it = 0; it < 15; ++it) {
        const unsigned mid = (lo + hi) >> 1;
        int c = 0;
#pragma unroll
        for (int j = 0; j < 8; ++j) c += ((unsigned)v0[j] <= mid) + ((unsigned)v1[j] <= mid);
        c = wred_sum_i(c);
        if (c >= TOPK) hi = mid; else lo = mid + 1;
    }
    if (lane == 0) {
        u16 b = (u16)lo;
        _Float16 h = __builtin_bit_cast(_Float16, b);
        tauB[row] = (float)h + 2.0f;   // upper bound on true 21st d2 + fp16 slack
    }
}

// ---------------- kernel 3b (layout A only): scan strip -> candidates ----
// Exactly-once rules: row-side (list[r]): d2<tau[r] && (r>=1024 || r>=c)
//                     col-side (list[c]): d2<tau[c] && (r>=1024 || r>c)
// Covers all pairs touching cols 0..1023; filter then skips tiles i<8.
__global__ __launch_bounds__(256) void strip_scan_kernel(const u16* __restrict__ d2h,
                                                         const float* __restrict__ tauB,
                                                         float* __restrict__ cand_g,
                                                         int* __restrict__ cnt_g) {
    __shared__ float tauC[1024];
    const int tid = threadIdx.x;
#pragma unroll
    for (int k = 0; k < 4; ++k) tauC[tid + k * 256] = tauB[tid + k * 256];
    __syncthreads();

    const int row  = blockIdx.x * 4 + (tid >> 6);
    const int c0   = (tid & 63) * 16;
    const float taur = tauB[row];
    const bool  rge  = (row >= 1024);

    const us8* p = (const us8*)(d2h + (size_t)row * 1024 + c0);
    us8 v0 = p[0];
    us8 v1 = p[1];

#pragma unroll
    for (int e = 0; e < 16; ++e) {
        const int c = c0 + e;
        const u16 hb = (e < 8) ? (u16)v0[e] : (u16)v1[e - 8];
        const float d2 = (float)__builtin_bit_cast(_Float16, hb);
        if (d2 < taur && (rge || row >= c)) {
            const int g = atomicAdd(&cnt_g[row], 1);
            if (g < CAPG) cand_g[(size_t)row * CAPG + g] = d2;
        }
        if (d2 < tauC[c] && (rge || row > c)) {
            const int g = atomicAdd(&cnt_g[c], 1);
            if (g < CAPG) cand_g[(size_t)c * CAPG + g] = d2;
        }
    }
}

// ---------------- kernel 4: SYMMETRIC upper-triangle GEMM + two-sided filter ----
// Tiles (i,j), SUB<=i<=j<64; SUB=8 when the strip-scan covers i<8 (layout A).
// R6-proven config: CAPL=8, 44032 B LDS, 3 blocks/CU.
__global__ __launch_bounds__(256, 3) void gemm_filter_sym(const u16* __restrict__ Xh,
                                                          const float* __restrict__ norms,
                                                          const float* __restrict__ tauB,
                                                          float* __restrict__ cand_g,
                                                          int* __restrict__ cnt_g,
                                                          const int SUB) {
    __shared__ __align__(16) u16 As[128 * 64];       // 16384 B
    __shared__ __align__(16) u16 Bs[128 * 64];       // 16384 B
    __shared__ float candR[128 * CAPL];              //  4096 B
    __shared__ float candC[128 * CAPL];              //  4096 B
    __shared__ int   cntR[128];
    __shared__ int   cntC[128];
    __shared__ float nAs[128], nBs[128], tA[128], tB[128];

    const int tid  = threadIdx.x;
    const int lane = tid & 63;
    const int wid  = tid >> 6;
    const int wr   = wid >> 1;
    const int wc   = wid & 1;
    const int l16  = lane >> 4;
    const int l15  = lane & 15;

    // m204 bijective XCD swizzle over nwg = gridDim.x
    const int nwg = gridDim.x;
    const int q   = nwg >> 3, rr = nwg & 7;
    const int xcd = blockIdx.x & 7;
    const int idx = blockIdx.x >> 3;
    const int b   = (xcd < rr ? xcd * (q + 1) : rr * (q + 1) + (xcd - rr) * q) + idx;

    // triangular decode over NT=64-SUB: b = j'(j'+1)/2 + i', i'<=j'
    int j = (int)((sqrtf(8.0f * (float)b + 1.0f) - 1.0f) * 0.5f);
    while ((j + 1) * (j + 2) / 2 <= b) ++j;
    while (j * (j + 1) / 2 > b) --j;
    const int i = b - j * (j + 1) / 2;
    const int r0 = (i + SUB) * 128;
    const int c0 = (j + SUB) * 128;
    const bool diag = (i == j);

    if (tid < 128) {
        nAs[tid] = norms[r0 + tid];
        tA[tid]  = tauB[r0 + tid];
        nBs[tid] = norms[c0 + tid];
        tB[tid]  = tauB[c0 + tid];
        cntR[tid] = 0;
        cntC[tid] = 0;
    }

    // staging geometry: 8 lanes per 128B row; T2 source-side XOR swizzle
    const int rb  = tid >> 3;
    const int chS = (tid & 7) ^ ((tid >> 3) & 7);
    const int lofs = tid * 8;

    f32x4 acc[4][4];
#pragma unroll
    for (int m = 0; m < 4; ++m)
#pragma unroll
        for (int n = 0; n < 4; ++n) {
            f32x4 z = {0.f, 0.f, 0.f, 0.f};
            acc[m][n] = z;
        }

    for (int ks = 0; ks < KSTEPS; ++ks) {
        const int kofs = ks * 64 + chS * 8;
#pragma unroll
        for (int it = 0; it < 4; ++it) {
            const int r = it * 32 + rb;
            gload16(Xh + (size_t)(r0 + r) * D_DIM + kofs, &As[it * 2048 + lofs]);
            gload16(Xh + (size_t)(c0 + r) * D_DIM + kofs, &Bs[it * 2048 + lofs]);
        }
        __syncthreads();
#pragma unroll
        for (int kk = 0; kk < 2; ++kk) {
            half8 af[4], bf[4];
#pragma unroll
            for (int m = 0; m < 4; ++m) {
                const int ra = wr * 64 + m * 16 + l15;
                const int ch = (kk * 4 + l16) ^ (ra & 7);
                af[m] = *reinterpret_cast<const half8*>(&As[ra * 64 + ch * 8]);
            }
#pragma unroll
            for (int n = 0; n < 4; ++n) {
                const int rc = wc * 64 + n * 16 + l15;
                const int ch = (kk * 4 + l16) ^ (rc & 7);
                bf[n] = *reinterpret_cast<const half8*>(&Bs[rc * 64 + ch * 8]);
            }
#pragma unroll
            for (int m = 0; m < 4; ++m)
#pragma unroll
                for (int n = 0; n < 4; ++n)
                    acc[m][n] = __builtin_amdgcn_mfma_f32_16x16x32_f16(af[m], bf[n], acc[m][n], 0, 0, 0);
        }
        __syncthreads();
    }

    // ---- two-sided filter epilogue ----
    float nBc[4], tBc[4];
#pragma unroll
    for (int n = 0; n < 4; ++n) {
        const int ci = wc * 64 + n * 16 + l15;
        nBc[n] = nBs[ci];
        tBc[n] = tB[ci];
    }

#pragma unroll
    for (int m = 0; m < 4; ++m)
#pragma unroll
        for (int r = 0; r < 4; ++r) {
            const int ri = wr * 64 + m * 16 + l16 * 4 + r;
            const float na = nAs[ri];
            const float ta = tA[ri];
#pragma unroll
            for (int n = 0; n < 4; ++n) {
                const float val = na + nBc[n] - 2.0f * acc[m][n][r];
                if (val < ta) {                      // row-side candidate
                    const int idx2 = atomicAdd(&cntR[ri], 1);
                    if (idx2 < CAPL) candR[ri * CAPL + idx2] = val;
                    else {
                        const int g = atomicAdd(&cnt_g[r0 + ri], 1);
                        if (g < CAPG) cand_g[(size_t)(r0 + ri) * CAPG + g] = val;
                    }
                }
                if (!diag && val < tBc[n]) {         // col-side candidate (symmetry)
                    const int ci = wc * 64 + n * 16 + l15;
                    const int idx2 = atomicAdd(&cntC[ci], 1);
                    if (idx2 < CAPL) candC[ci * CAPL + idx2] = val;
                    else {
                        const int g = atomicAdd(&cnt_g[c0 + ci], 1);
                        if (g < CAPG) cand_g[(size_t)(c0 + ci) * CAPG + g] = val;
                    }
                }
            }
        }

    __syncthreads();
    if (tid < 128) {
        {   // row-side writeout
            const int row = r0 + tid;
            const int c = (cntR[tid] < CAPL) ? cntR[tid] : CAPL;
            if (c > 0) {
                const int base = atomicAdd(&cnt_g[row], c);
                for (int qq = 0; qq < c; ++qq) {
                    const int s = base + qq;
                    if (s < CAPG) cand_g[(size_t)row * CAPG + s] = candR[tid * CAPL + qq];
                }
            }
        }
        if (!diag) {   // col-side writeout
            const int row = c0 + tid;
            const int c = (cntC[tid] < CAPL) ? cntC[tid] : CAPL;
            if (c > 0) {
                const int base = atomicAdd(&cnt_g[row], c);
                for (int qq = 0; qq < c; ++qq) {
                    const int s = base + qq;
                    if (s < CAPG) cand_g[(size_t)row * CAPG + s] = candC[tid * CAPL + qq];
                }
            }
        }
    }
}

// ---------------- kernel 5: per-row top-21 stats + LID ----
__global__ __launch_bounds__(256) void finalize_kernel(const float* __restrict__ cand_g,
                                                       const int* __restrict__ cnt_g,
                                                       float* __restrict__ out) {
    const int tid  = threadIdx.x;
    const int lane = tid & 63;
    const int row  = blockIdx.x * 4 + (tid >> 6);

    int cnt = cnt_g[row];
    if (cnt > CAPG) cnt = CAPG;
    const float INFV = __uint_as_float(0x7F800000u);

    float v[7];
    unsigned b[7];
#pragma unroll
    for (int j = 0; j < 7; ++j) {
        const int s = lane + 64 * j;
        v[j] = (s < cnt) ? fmaxf(cand_g[(size_t)row * CAPG + s], 0.0f) : INFV;
        b[j] = __float_as_uint(v[j]);
    }

    unsigned lo = 0, hi = 0x7F7FFFFFu;
#pragma unroll
    for (int it = 0; it < 31; ++it) {
        const unsigned mid = (lo + hi) >> 1;
        int c = 0;
#pragma unroll
        for (int j = 0; j < 7; ++j) c += (b[j] <= mid);
        c = wred_sum_i(c);
        if (c >= TOPK) hi = mid; else lo = mid + 1;
    }
    const float th = __uint_as_float(lo);

    int clt = 0;
    float slt = 0.f, mn = INFV;
#pragma unroll
    for (int j = 0; j < 7; ++j) {
        if (b[j] < lo) {
            clt += 1;
            slt += sqrtf(fmaxf(v[j], 1e-12f));
        }
        mn = fminf(mn, v[j]);
    }
    clt = wred_sum_i(clt);
    slt = wred_sum_f(slt);
    mn  = wred_min_f(mn);

    if (lane == 0) {
        const float a20 = sqrtf(fmaxf(th, 1e-12f));
        const float a0  = sqrtf(fmaxf(mn, 1e-12f));
        const float S21 = slt + (float)(TOPK - clt) * a20;
        const float m   = (S21 - a0 - a20) * (1.0f / 19.0f);
        const float lid = m / (a20 - m);
        out[row] = -fabsf(logf(lid));
    }
}

extern "C" void kernel_launch(void* const* d_in, const int* in_sizes, int n_in,
                              void* d_out, int out_size, void* d_ws, size_t ws_size,
                              hipStream_t stream) {
    const float* X = (const float*)d_in[0];
    float* out = (float*)d_out;
    char* ws = (char*)d_ws;

    u16*   Xh    = (u16*)ws;                      // 12,582,912 B
    float* norms = (float*)(ws + 12582912);       //     32,768 B
    float* tauB  = (float*)(ws + 12615680);       //     32,768 B
    int*   cnt_g = (int*)(ws + 12648448);         //     32,768 B
    u16*   d2h   = (u16*)(ws + 12681216);         // 16,777,216 B (8192x1024 fp16)

    // Layout A (ws >= 44.14 MB): cand_g separate -> strip-scan covers tiles i<8.
    // Layout B: cand_g aliases d2h (R6-proven full-triangle path).
    const bool bigws = (ws_size >= (size_t)44138496);
    float* cand_g = bigws ? (float*)(ws + 29458432) : (float*)(ws + 12681216);
    const int SUB  = bigws ? 8 : 0;
    const int NT   = 64 - SUB;
    const int nTiles = NT * (NT + 1) / 2;         // 1596 or 2080

    prep_kernel<<<N_PTS / 4, 256, 0, stream>>>(X, Xh, norms, cnt_g);
    gemm_tau_kernel<<<512, 256, 0, stream>>>(Xh, norms, d2h);
    tau_select_kernel<<<N_PTS / 4, 256, 0, stream>>>(d2h, tauB);
    if (bigws)
        strip_scan_kernel<<<N_PTS / 4, 256, 0, stream>>>(d2h, tauB, cand_g, cnt_g);
    gemm_filter_sym<<<nTiles, 256, 0, stream>>>(Xh, norms, tauB, cand_g, cnt_g, SUB);
    finalize_kernel<<<N_PTS / 4, 256, 0, stream>>>(cand_g, cnt_g, out);
}

// Round 12
// 149.623 us; speedup vs baseline: 1.3930x; 1.3930x over previous
//
#include <hip/hip_runtime.h>
#include <hip/hip_fp16.h>

typedef unsigned short u16;
using f32x4 = __attribute__((ext_vector_type(4))) float;
using half8 = __attribute__((ext_vector_type(8))) _Float16;
using us8   = __attribute__((ext_vector_type(8))) unsigned short;
using us4   = __attribute__((ext_vector_type(4))) unsigned short;

#define N_PTS 8192
#define D_DIM 768
#define TOPK  21
#define KSTEPS 12
#define CAPL  8
#define CAPG  448

// ---------------- async global->LDS (16B per lane) ----------------
__device__ __forceinline__ void gload16(const void* g, void* l) {
    __builtin_amdgcn_global_load_lds(
        (const __attribute__((address_space(1))) void*)g,
        (__attribute__((address_space(3))) void*)l,
        16, 0, 0);
}

// ---------------- wave (64-lane) reductions ----------------
__device__ __forceinline__ int wred_sum_i(int c) {
#pragma unroll
    for (int o = 32; o >= 1; o >>= 1) c += __shfl_xor(c, o, 64);
    return c;
}
__device__ __forceinline__ float wred_sum_f(float c) {
#pragma unroll
    for (int o = 32; o >= 1; o >>= 1) c += __shfl_xor(c, o, 64);
    return c;
}
__device__ __forceinline__ float wred_min_f(float c) {
#pragma unroll
    for (int o = 32; o >= 1; o >>= 1) c = fminf(c, __shfl_xor(c, o, 64));
    return c;
}

// ---------------- kernel 1: fp32 -> fp16 + row norms (vectorized) ----
__global__ __launch_bounds__(256) void prep_kernel(const float* __restrict__ X,
                                                   u16* __restrict__ Xh,
                                                   float* __restrict__ norms,
                                                   int* __restrict__ cnt_g) {
    const int tid  = threadIdx.x;
    const int lane = tid & 63;
    const int row  = blockIdx.x * 4 + (tid >> 6);
    const float4* xr = (const float4*)(X + (size_t)row * D_DIM);
    us4* hr = (us4*)(Xh + (size_t)row * D_DIM);
    float s = 0.f;
#pragma unroll
    for (int j = 0; j < 3; ++j) {
        const float4 v = xr[lane + j * 64];
        _Float16 h0 = (_Float16)v.x, h1 = (_Float16)v.y,
                 h2 = (_Float16)v.z, h3 = (_Float16)v.w;
        us4 u;
        u[0] = __builtin_bit_cast(u16, h0);
        u[1] = __builtin_bit_cast(u16, h1);
        u[2] = __builtin_bit_cast(u16, h2);
        u[3] = __builtin_bit_cast(u16, h3);
        hr[lane + j * 64] = u;
        const float f0 = (float)h0, f1 = (float)h1, f2 = (float)h2, f3 = (float)h3;
        s += f0 * f0 + f1 * f1 + f2 * f2 + f3 * f3;
    }
#pragma unroll
    for (int o = 32; o >= 1; o >>= 1) s += __shfl_down(s, o, 64);
    if (lane == 0) {
        norms[row] = s;
        cnt_g[row] = 0;
    }
}

// ---------------- kernel 2: sample GEMM (cols 0..1023) -> d2 as fp16 ----
// Same 128x128 structure as filter, now WITH the T2 source-side swizzle.
__global__ __launch_bounds__(256, 4) void gemm_tau_kernel(const u16* __restrict__ Xh,
                                                          const float* __restrict__ norms,
                                                          u16* __restrict__ d2h) {
    __shared__ __align__(16) u16 As[128 * 64];
    __shared__ __align__(16) u16 Bs[128 * 64];
    __shared__ float nAs[128];
    __shared__ float nBs[128];

    const int tid  = threadIdx.x;
    const int lane = tid & 63;
    const int wid  = tid >> 6;
    const int wr   = wid >> 1;
    const int wc   = wid & 1;
    const int l16  = lane >> 4;
    const int l15  = lane & 15;

    const int bid = blockIdx.x;
    const int swz = (bid & 7) * 64 + (bid >> 3);
    const int rowTile = swz >> 3;
    const int chunk   = swz & 7;
    const int r0 = rowTile * 128;
    const int cb = chunk * 128;

    if (tid < 128) {
        nAs[tid] = norms[r0 + tid];
        nBs[tid] = norms[cb + tid];
    }

    const int rb   = tid >> 3;
    const int chS  = (tid & 7) ^ ((tid >> 3) & 7);   // T2 pre-swizzled source chunk
    const int lofs = tid * 8;                        // linear LDS dest

    f32x4 acc[4][4];
#pragma unroll
    for (int m = 0; m < 4; ++m)
#pragma unroll
        for (int n = 0; n < 4; ++n) {
            f32x4 z = {0.f, 0.f, 0.f, 0.f};
            acc[m][n] = z;
        }

    for (int ks = 0; ks < KSTEPS; ++ks) {
        const int kofs = ks * 64 + chS * 8;
#pragma unroll
        for (int it = 0; it < 4; ++it) {
            const int r = it * 32 + rb;
            gload16(Xh + (size_t)(r0 + r) * D_DIM + kofs, &As[it * 2048 + lofs]);
            gload16(Xh + (size_t)(cb + r) * D_DIM + kofs, &Bs[it * 2048 + lofs]);
        }
        __syncthreads();
#pragma unroll
        for (int kk = 0; kk < 2; ++kk) {
            half8 af[4], bf[4];
#pragma unroll
            for (int m = 0; m < 4; ++m) {
                const int ra = wr * 64 + m * 16 + l15;
                const int ch = (kk * 4 + l16) ^ (ra & 7);
                af[m] = *reinterpret_cast<const half8*>(&As[ra * 64 + ch * 8]);
            }
#pragma unroll
            for (int n = 0; n < 4; ++n) {
                const int rc = wc * 64 + n * 16 + l15;
                const int ch = (kk * 4 + l16) ^ (rc & 7);
                bf[n] = *reinterpret_cast<const half8*>(&Bs[rc * 64 + ch * 8]);
            }
#pragma unroll
            for (int m = 0; m < 4; ++m)
#pragma unroll
                for (int n = 0; n < 4; ++n)
                    acc[m][n] = __builtin_amdgcn_mfma_f32_16x16x32_f16(af[m], bf[n], acc[m][n], 0, 0, 0);
        }
        __syncthreads();
    }

    float nAr[4][4], nBc[4];
#pragma unroll
    for (int m = 0; m < 4; ++m)
#pragma unroll
        for (int r = 0; r < 4; ++r) nAr[m][r] = nAs[wr * 64 + m * 16 + l16 * 4 + r];
#pragma unroll
    for (int n = 0; n < 4; ++n) nBc[n] = nBs[wc * 64 + n * 16 + l15];

#pragma unroll
    for (int m = 0; m < 4; ++m)
#pragma unroll
        for (int n = 0; n < 4; ++n)
#pragma unroll
            for (int r = 0; r < 4; ++r) {
                const int ri = r0 + wr * 64 + m * 16 + l16 * 4 + r;
                const int ci = cb + wc * 64 + n * 16 + l15;
                float d2 = fmaxf(nAr[m][r] + nBc[n] - 2.0f * acc[m][n][r], 0.0f);
                _Float16 h = (_Float16)d2;
                d2h[(size_t)ri * 1024 + ci] = __builtin_bit_cast(u16, h);
            }
}

// ---------------- kernel 3: per-row 21st-smallest of sample (bit search) ----
__global__ __launch_bounds__(256) void tau_select_kernel(const u16* __restrict__ d2h,
                                                         float* __restrict__ tauB) {
    const int tid  = threadIdx.x;
    const int lane = tid & 63;
    const int row  = blockIdx.x * 4 + (tid >> 6);

    const us8* p = (const us8*)(d2h + (size_t)row * 1024);
    us8 v0 = p[lane * 2];
    us8 v1 = p[lane * 2 + 1];

    unsigned lo = 0, hi = 0x7BFF;
#pragma unroll
    for (int it = 0; it < 15; ++it) {
        const unsigned mid = (lo + hi) >> 1;
        int c = 0;
#pragma unroll
        for (int j = 0; j < 8; ++j) c += ((unsigned)v0[j] <= mid) + ((unsigned)v1[j] <= mid);
        c = wred_sum_i(c);
        if (c >= TOPK) hi = mid; else lo = mid + 1;
    }
    if (lane == 0) {
        u16 b = (u16)lo;
        _Float16 h = __builtin_bit_cast(_Float16, b);
        tauB[row] = (float)h + 2.0f;   // upper bound on true 21st d2 + fp16 slack
    }
}

// ---------------- kernel 4: full upper-triangle, two-sided filter ----
// 2080 tiles (i<=j<64). SUBT=8: tiles with i<8 skip the GEMM and read their
// 128x128 d2 block from d2h (val = d2h[c][r], r<1024) -> same LDS epilogue.
// SUBT=0: all-compute (R6-exact, used when cand_g must alias d2h).
template<int SUBT>
__global__ __launch_bounds__(256, 3) void gemm_filter_sym(const u16* __restrict__ Xh,
                                                          const float* __restrict__ norms,
                                                          const float* __restrict__ tauB,
                                                          const u16* __restrict__ d2h,
                                                          float* __restrict__ cand_g,
                                                          int* __restrict__ cnt_g) {
    __shared__ __align__(16) u16 As[128 * 64];       // 16384 B
    __shared__ __align__(16) u16 Bs[128 * 64];       // 16384 B
    __shared__ float candR[128 * CAPL];              //  4096 B
    __shared__ float candC[128 * CAPL];              //  4096 B
    __shared__ int   cntR[128];
    __shared__ int   cntC[128];
    __shared__ float nAs[128], nBs[128], tA[128], tB[128];

    const int tid  = threadIdx.x;
    const int lane = tid & 63;
    const int wid  = tid >> 6;
    const int wr   = wid >> 1;
    const int wc   = wid & 1;
    const int l16  = lane >> 4;
    const int l15  = lane & 15;

    // XCD swizzle (2080 = 8 * 260) then triangular decode: b = j*(j+1)/2 + i
    const int b = (blockIdx.x & 7) * 260 + (blockIdx.x >> 3);
    int j = (int)((sqrtf(8.0f * (float)b + 1.0f) - 1.0f) * 0.5f);
    while ((j + 1) * (j + 2) / 2 <= b) ++j;
    while (j * (j + 1) / 2 > b) --j;
    const int i = b - j * (j + 1) / 2;
    const int r0 = i * 128;
    const int c0 = j * 128;
    const bool diag = (i == j);
    const bool strip = (SUBT > 0) && (i < SUBT);

    if (tid < 128) {
        nAs[tid] = norms[r0 + tid];
        tA[tid]  = tauB[r0 + tid];
        nBs[tid] = norms[c0 + tid];
        tB[tid]  = tauB[c0 + tid];
        cntR[tid] = 0;
        cntC[tid] = 0;
    }

    if (strip) {
        // ---- read-tile path: val(rloc,cc) = d2h[c0+cc][r0+rloc], r0+127 < 1024 ----
        __syncthreads();                          // tA/tB/cnt ready
        const int cc   = tid >> 1;                // local col 0..127
        const int half = tid & 1;                 // which 64-row half
        const float tBcc = tB[cc];
        const us8* src = (const us8*)(d2h + (size_t)(c0 + cc) * 1024 + r0 + half * 64);
        us8 v[8];
#pragma unroll
        for (int q = 0; q < 8; ++q) v[q] = src[q];
#pragma unroll
        for (int q = 0; q < 8; ++q)
#pragma unroll
            for (int k = 0; k < 8; ++k) {
                const int rloc = half * 64 + q * 8 + k;
                const float val = (float)__builtin_bit_cast(_Float16, (u16)v[q][k]);
                if (val < tA[rloc]) {             // row-side
                    const int idx2 = atomicAdd(&cntR[rloc], 1);
                    if (idx2 < CAPL) candR[rloc * CAPL + idx2] = val;
                    else {
                        const int g = atomicAdd(&cnt_g[r0 + rloc], 1);
                        if (g < CAPG) cand_g[(size_t)(r0 + rloc) * CAPG + g] = val;
                    }
                }
                if (!diag && val < tBcc) {        // col-side
                    const int idx2 = atomicAdd(&cntC[cc], 1);
                    if (idx2 < CAPL) candC[cc * CAPL + idx2] = val;
                    else {
                        const int g = atomicAdd(&cnt_g[c0 + cc], 1);
                        if (g < CAPG) cand_g[(size_t)(c0 + cc) * CAPG + g] = val;
                    }
                }
            }
    } else {
        // ---- compute path (R6-proven) ----
        const int rb  = tid >> 3;
        const int chS = (tid & 7) ^ ((tid >> 3) & 7);
        const int lofs = tid * 8;

        f32x4 acc[4][4];
#pragma unroll
        for (int m = 0; m < 4; ++m)
#pragma unroll
            for (int n = 0; n < 4; ++n) {
                f32x4 z = {0.f, 0.f, 0.f, 0.f};
                acc[m][n] = z;
            }

        for (int ks = 0; ks < KSTEPS; ++ks) {
            const int kofs = ks * 64 + chS * 8;
#pragma unroll
            for (int it = 0; it < 4; ++it) {
                const int r = it * 32 + rb;
                gload16(Xh + (size_t)(r0 + r) * D_DIM + kofs, &As[it * 2048 + lofs]);
                gload16(Xh + (size_t)(c0 + r) * D_DIM + kofs, &Bs[it * 2048 + lofs]);
            }
            __syncthreads();
#pragma unroll
            for (int kk = 0; kk < 2; ++kk) {
                half8 af[4], bf[4];
#pragma unroll
                for (int m = 0; m < 4; ++m) {
                    const int ra = wr * 64 + m * 16 + l15;
                    const int ch = (kk * 4 + l16) ^ (ra & 7);
                    af[m] = *reinterpret_cast<const half8*>(&As[ra * 64 + ch * 8]);
                }
#pragma unroll
                for (int n = 0; n < 4; ++n) {
                    const int rc = wc * 64 + n * 16 + l15;
                    const int ch = (kk * 4 + l16) ^ (rc & 7);
                    bf[n] = *reinterpret_cast<const half8*>(&Bs[rc * 64 + ch * 8]);
                }
#pragma unroll
                for (int m = 0; m < 4; ++m)
#pragma unroll
                    for (int n = 0; n < 4; ++n)
                        acc[m][n] = __builtin_amdgcn_mfma_f32_16x16x32_f16(af[m], bf[n], acc[m][n], 0, 0, 0);
            }
            __syncthreads();
        }

        float nBc[4], tBc[4];
#pragma unroll
        for (int n = 0; n < 4; ++n) {
            const int ci = wc * 64 + n * 16 + l15;
            nBc[n] = nBs[ci];
            tBc[n] = tB[ci];
        }

#pragma unroll
        for (int m = 0; m < 4; ++m)
#pragma unroll
            for (int r = 0; r < 4; ++r) {
                const int ri = wr * 64 + m * 16 + l16 * 4 + r;
                const float na = nAs[ri];
                const float ta = tA[ri];
#pragma unroll
                for (int n = 0; n < 4; ++n) {
                    const float val = na + nBc[n] - 2.0f * acc[m][n][r];
                    if (val < ta) {                      // row-side
                        const int idx2 = atomicAdd(&cntR[ri], 1);
                        if (idx2 < CAPL) candR[ri * CAPL + idx2] = val;
                        else {
                            const int g = atomicAdd(&cnt_g[r0 + ri], 1);
                            if (g < CAPG) cand_g[(size_t)(r0 + ri) * CAPG + g] = val;
                        }
                    }
                    if (!diag && val < tBc[n]) {         // col-side (symmetry)
                        const int ci = wc * 64 + n * 16 + l15;
                        const int idx2 = atomicAdd(&cntC[ci], 1);
                        if (idx2 < CAPL) candC[ci * CAPL + idx2] = val;
                        else {
                            const int g = atomicAdd(&cnt_g[c0 + ci], 1);
                            if (g < CAPG) cand_g[(size_t)(c0 + ci) * CAPG + g] = val;
                        }
                    }
                }
            }
    }

    __syncthreads();
    if (tid < 128) {
        {   // row-side writeout
            const int row = r0 + tid;
            const int c = (cntR[tid] < CAPL) ? cntR[tid] : CAPL;
            if (c > 0) {
                const int base = atomicAdd(&cnt_g[row], c);
                for (int qq = 0; qq < c; ++qq) {
                    const int s = base + qq;
                    if (s < CAPG) cand_g[(size_t)row * CAPG + s] = candR[tid * CAPL + qq];
                }
            }
        }
        if (!diag) {   // col-side writeout
            const int row = c0 + tid;
            const int c = (cntC[tid] < CAPL) ? cntC[tid] : CAPL;
            if (c > 0) {
                const int base = atomicAdd(&cnt_g[row], c);
                for (int qq = 0; qq < c; ++qq) {
                    const int s = base + qq;
                    if (s < CAPG) cand_g[(size_t)row * CAPG + s] = candC[tid * CAPL + qq];
                }
            }
        }
    }
}

// ---------------- kernel 5: per-row top-21 stats + LID ----
__global__ __launch_bounds__(256) void finalize_kernel(const float* __restrict__ cand_g,
                                                       const int* __restrict__ cnt_g,
                                                       float* __restrict__ out) {
    const int tid  = threadIdx.x;
    const int lane = tid & 63;
    const int row  = blockIdx.x * 4 + (tid >> 6);

    int cnt = cnt_g[row];
    if (cnt > CAPG) cnt = CAPG;
    const float INFV = __uint_as_float(0x7F800000u);

    float v[7];
    unsigned b[7];
#pragma unroll
    for (int j = 0; j < 7; ++j) {
        const int s = lane + 64 * j;
        v[j] = (s < cnt) ? fmaxf(cand_g[(size_t)row * CAPG + s], 0.0f) : INFV;
        b[j] = __float_as_uint(v[j]);
    }

    unsigned lo = 0, hi = 0x7F7FFFFFu;
#pragma unroll
    for (int it = 0; it < 31; ++it) {
        const unsigned mid = (lo + hi) >> 1;
        int c = 0;
#pragma unroll
        for (int j = 0; j < 7; ++j) c += (b[j] <= mid);
        c = wred_sum_i(c);
        if (c >= TOPK) hi = mid; else lo = mid + 1;
    }
    const float th = __uint_as_float(lo);

    int clt = 0;
    float slt = 0.f, mn = INFV;
#pragma unroll
    for (int j = 0; j < 7; ++j) {
        if (b[j] < lo) {
            clt += 1;
            slt += sqrtf(fmaxf(v[j], 1e-12f));
        }
        mn = fminf(mn, v[j]);
    }
    clt = wred_sum_i(clt);
    slt = wred_sum_f(slt);
    mn  = wred_min_f(mn);

    if (lane == 0) {
        const float a20 = sqrtf(fmaxf(th, 1e-12f));
        const float a0  = sqrtf(fmaxf(mn, 1e-12f));
        const float S21 = slt + (float)(TOPK - clt) * a20;
        const float m   = (S21 - a0 - a20) * (1.0f / 19.0f);
        const float lid = m / (a20 - m);
        out[row] = -fabsf(logf(lid));
    }
}

extern "C" void kernel_launch(void* const* d_in, const int* in_sizes, int n_in,
                              void* d_out, int out_size, void* d_ws, size_t ws_size,
                              hipStream_t stream) {
    const float* X = (const float*)d_in[0];
    float* out = (float*)d_out;
    char* ws = (char*)d_ws;

    u16*   Xh    = (u16*)ws;                      // 12,582,912 B
    float* norms = (float*)(ws + 12582912);       //     32,768 B
    float* tauB  = (float*)(ws + 12615680);       //     32,768 B
    int*   cnt_g = (int*)(ws + 12648448);         //     32,768 B
    u16*   d2h   = (u16*)(ws + 12681216);         // 16,777,216 B (8192x1024 fp16)

    // Layout A (ws >= 44.14 MB): cand_g separate -> filter read-tiles for i<8.
    // Layout B: cand_g aliases d2h -> all-compute triangle (R6-exact).
    const bool bigws = (ws_size >= (size_t)44138496);
    float* cand_g = bigws ? (float*)(ws + 29458432) : (float*)(ws + 12681216);

    prep_kernel<<<N_PTS / 4, 256, 0, stream>>>(X, Xh, norms, cnt_g);
    gemm_tau_kernel<<<512, 256, 0, stream>>>(Xh, norms, d2h);
    tau_select_kernel<<<N_PTS / 4, 256, 0, stream>>>(d2h, tauB);
    if (bigws)
        gemm_filter_sym<8><<<2080, 256, 0, stream>>>(Xh, norms, tauB, d2h, cand_g, cnt_g);
    else
        gemm_filter_sym<0><<<2080, 256, 0, stream>>>(Xh, norms, tauB, d2h, cand_g, cnt_g);
    finalize_kernel<<<N_PTS / 4, 256, 0, stream>>>(cand_g, cnt_g, out);
}

// Round 13
// 148.245 us; speedup vs baseline: 1.4060x; 1.0093x over previous
//
#include <hip/hip_runtime.h>
#include <hip/hip_fp16.h>

typedef unsigned short u16;
using f32x4 = __attribute__((ext_vector_type(4))) float;
using half8 = __attribute__((ext_vector_type(8))) _Float16;
using us8   = __attribute__((ext_vector_type(8))) unsigned short;
using us4   = __attribute__((ext_vector_type(4))) unsigned short;

#define N_PTS 8192
#define D_DIM 768
#define TOPK  21
#define KSTEPS 12
#define CAPL  8
#define CAPG  448
#define NCOMP 1596   // 56*57/2 compute tiles (i>=8)
#define NREAD 484    // read tiles (i<8)

// ---------------- async global->LDS (16B per lane) ----------------
__device__ __forceinline__ void gload16(const void* g, void* l) {
    __builtin_amdgcn_global_load_lds(
        (const __attribute__((address_space(1))) void*)g,
        (__attribute__((address_space(3))) void*)l,
        16, 0, 0);
}

// ---------------- wave (64-lane) reductions ----------------
__device__ __forceinline__ int wred_sum_i(int c) {
#pragma unroll
    for (int o = 32; o >= 1; o >>= 1) c += __shfl_xor(c, o, 64);
    return c;
}
__device__ __forceinline__ float wred_sum_f(float c) {
#pragma unroll
    for (int o = 32; o >= 1; o >>= 1) c += __shfl_xor(c, o, 64);
    return c;
}
__device__ __forceinline__ float wred_min_f(float c) {
#pragma unroll
    for (int o = 32; o >= 1; o >>= 1) c = fminf(c, __shfl_xor(c, o, 64));
    return c;
}

// round tau up to the next fp16 boundary (bit pattern), exact superset compare
__device__ __forceinline__ u16 tau_h_up(float t) {
    u16 h = __builtin_bit_cast(u16, (_Float16)t);
    if ((float)__builtin_bit_cast(_Float16, h) < t) ++h;
    return h;
}

// ---------------- kernel 1: fp32 -> fp16 + row norms (vectorized) ----
__global__ __launch_bounds__(256) void prep_kernel(const float* __restrict__ X,
                                                   u16* __restrict__ Xh,
                                                   float* __restrict__ norms,
                                                   int* __restrict__ cnt_g) {
    const int tid  = threadIdx.x;
    const int lane = tid & 63;
    const int row  = blockIdx.x * 4 + (tid >> 6);
    const float4* xr = (const float4*)(X + (size_t)row * D_DIM);
    us4* hr = (us4*)(Xh + (size_t)row * D_DIM);
    float s = 0.f;
#pragma unroll
    for (int j = 0; j < 3; ++j) {
        const float4 v = xr[lane + j * 64];
        _Float16 h0 = (_Float16)v.x, h1 = (_Float16)v.y,
                 h2 = (_Float16)v.z, h3 = (_Float16)v.w;
        us4 u;
        u[0] = __builtin_bit_cast(u16, h0);
        u[1] = __builtin_bit_cast(u16, h1);
        u[2] = __builtin_bit_cast(u16, h2);
        u[3] = __builtin_bit_cast(u16, h3);
        hr[lane + j * 64] = u;
        const float f0 = (float)h0, f1 = (float)h1, f2 = (float)h2, f3 = (float)h3;
        s += f0 * f0 + f1 * f1 + f2 * f2 + f3 * f3;
    }
#pragma unroll
    for (int o = 32; o >= 1; o >>= 1) s += __shfl_down(s, o, 64);
    if (lane == 0) {
        norms[row] = s;
        cnt_g[row] = 0;
    }
}

// ---------------- kernel 2: sample GEMM (cols 0..1023) -> d2 as fp16 ----
__global__ __launch_bounds__(256, 4) void gemm_tau_kernel(const u16* __restrict__ Xh,
                                                          const float* __restrict__ norms,
                                                          u16* __restrict__ d2h) {
    __shared__ __align__(16) u16 As[128 * 64];
    __shared__ __align__(16) u16 Bs[128 * 64];
    __shared__ float nAs[128];
    __shared__ float nBs[128];

    const int tid  = threadIdx.x;
    const int lane = tid & 63;
    const int wid  = tid >> 6;
    const int wr   = wid >> 1;
    const int wc   = wid & 1;
    const int l16  = lane >> 4;
    const int l15  = lane & 15;

    const int bid = blockIdx.x;
    const int swz = (bid & 7) * 64 + (bid >> 3);
    const int rowTile = swz >> 3;
    const int chunk   = swz & 7;
    const int r0 = rowTile * 128;
    const int cb = chunk * 128;

    if (tid < 128) {
        nAs[tid] = norms[r0 + tid];
        nBs[tid] = norms[cb + tid];
    }

    const int rb   = tid >> 3;
    const int chS  = (tid & 7) ^ ((tid >> 3) & 7);
    const int lofs = tid * 8;

    f32x4 acc[4][4];
#pragma unroll
    for (int m = 0; m < 4; ++m)
#pragma unroll
        for (int n = 0; n < 4; ++n) {
            f32x4 z = {0.f, 0.f, 0.f, 0.f};
            acc[m][n] = z;
        }

    for (int ks = 0; ks < KSTEPS; ++ks) {
        const int kofs = ks * 64 + chS * 8;
#pragma unroll
        for (int it = 0; it < 4; ++it) {
            const int r = it * 32 + rb;
            gload16(Xh + (size_t)(r0 + r) * D_DIM + kofs, &As[it * 2048 + lofs]);
            gload16(Xh + (size_t)(cb + r) * D_DIM + kofs, &Bs[it * 2048 + lofs]);
        }
        __syncthreads();
#pragma unroll
        for (int kk = 0; kk < 2; ++kk) {
            half8 af[4], bf[4];
#pragma unroll
            for (int m = 0; m < 4; ++m) {
                const int ra = wr * 64 + m * 16 + l15;
                const int ch = (kk * 4 + l16) ^ (ra & 7);
                af[m] = *reinterpret_cast<const half8*>(&As[ra * 64 + ch * 8]);
            }
#pragma unroll
            for (int n = 0; n < 4; ++n) {
                const int rc = wc * 64 + n * 16 + l15;
                const int ch = (kk * 4 + l16) ^ (rc & 7);
                bf[n] = *reinterpret_cast<const half8*>(&Bs[rc * 64 + ch * 8]);
            }
#pragma unroll
            for (int m = 0; m < 4; ++m)
#pragma unroll
                for (int n = 0; n < 4; ++n)
                    acc[m][n] = __builtin_amdgcn_mfma_f32_16x16x32_f16(af[m], bf[n], acc[m][n], 0, 0, 0);
        }
        __syncthreads();
    }

    float nAr[4][4], nBc[4];
#pragma unroll
    for (int m = 0; m < 4; ++m)
#pragma unroll
        for (int r = 0; r < 4; ++r) nAr[m][r] = nAs[wr * 64 + m * 16 + l16 * 4 + r];
#pragma unroll
    for (int n = 0; n < 4; ++n) nBc[n] = nBs[wc * 64 + n * 16 + l15];

#pragma unroll
    for (int m = 0; m < 4; ++m)
#pragma unroll
        for (int n = 0; n < 4; ++n)
#pragma unroll
            for (int r = 0; r < 4; ++r) {
                const int ri = r0 + wr * 64 + m * 16 + l16 * 4 + r;
                const int ci = cb + wc * 64 + n * 16 + l15;
                float d2 = fmaxf(nAr[m][r] + nBc[n] - 2.0f * acc[m][n][r], 0.0f);
                _Float16 h = (_Float16)d2;
                d2h[(size_t)ri * 1024 + ci] = __builtin_bit_cast(u16, h);
            }
}

// ---------------- kernel 3: per-row 21st-smallest of sample (bit search) ----
__global__ __launch_bounds__(256) void tau_select_kernel(const u16* __restrict__ d2h,
                                                         float* __restrict__ tauB) {
    const int tid  = threadIdx.x;
    const int lane = tid & 63;
    const int row  = blockIdx.x * 4 + (tid >> 6);

    const us8* p = (const us8*)(d2h + (size_t)row * 1024);
    us8 v0 = p[lane * 2];
    us8 v1 = p[lane * 2 + 1];

    unsigned lo = 0, hi = 0x7BFF;
#pragma unroll
    for (int it = 0; it < 15; ++it) {
        const unsigned mid = (lo + hi) >> 1;
        int c = 0;
#pragma unroll
        for (int j = 0; j < 8; ++j) c += ((unsigned)v0[j] <= mid) + ((unsigned)v1[j] <= mid);
        c = wred_sum_i(c);
        if (c >= TOPK) hi = mid; else lo = mid + 1;
    }
    if (lane == 0) {
        u16 b = (u16)lo;
        _Float16 h = __builtin_bit_cast(_Float16, b);
        tauB[row] = (float)h + 2.0f;   // upper bound on true 21st d2 + fp16 slack
    }
}

// ---------------- kernel 4: full upper-triangle, two-sided filter ----
// SUBT=8 (layout A): blockIdx [0,1596) = compute tiles (i>=8, m204-swizzled);
//   [1596,2080) = read tiles (i<8) dispatched LAST (cheap tail), u16 bit-compare.
// SUBT=0 (layout B): all-compute full triangle (R6-exact).
template<int SUBT>
__global__ __launch_bounds__(256, 3) void gemm_filter_sym(const u16* __restrict__ Xh,
                                                          const float* __restrict__ norms,
                                                          const float* __restrict__ tauB,
                                                          const u16* __restrict__ d2h,
                                                          float* __restrict__ cand_g,
                                                          int* __restrict__ cnt_g) {
    __shared__ __align__(16) u16 As[128 * 64];       // 16384 B
    __shared__ __align__(16) u16 Bs[128 * 64];       // 16384 B
    __shared__ float candR[128 * CAPL];              //  4096 B
    __shared__ float candC[128 * CAPL];              //  4096 B
    __shared__ int   cntR[128];
    __shared__ int   cntC[128];
    __shared__ float nAs[128], nBs[128], tA[128], tB[128];
    __shared__ __align__(16) u16 tAh[128];           // 256 B (fp16-up tau bits)
    __shared__ u16 tBh[128];                         // 256 B

    const int tid  = threadIdx.x;
    const int lane = tid & 63;
    const int wid  = tid >> 6;
    const int wr   = wid >> 1;
    const int wc   = wid & 1;
    const int l16  = lane >> 4;
    const int l15  = lane & 15;

    int i, j;
    bool isRead = false;
    if (SUBT > 0) {
        if ((int)blockIdx.x < NCOMP) {
            // m204 bijective XCD swizzle over 1596 (q=199, r=4)
            const int xcd = blockIdx.x & 7, idx = blockIdx.x >> 3;
            const int b = (xcd < 4 ? xcd * 200 : 800 + (xcd - 4) * 199) + idx;
            int jj = (int)((sqrtf(8.0f * (float)b + 1.0f) - 1.0f) * 0.5f);
            while ((jj + 1) * (jj + 2) / 2 <= b) ++jj;
            while (jj * (jj + 1) / 2 > b) --jj;
            i = (b - jj * (jj + 1) / 2) + 8;
            j = jj + 8;
        } else {
            // read tiles last; m204 swizzle over 484 (q=60, r=4)
            const int bb = (int)blockIdx.x - NCOMP;
            const int xcd = bb & 7, idx = bb >> 3;
            int b = (xcd < 4 ? xcd * 61 : 244 + (xcd - 4) * 60) + idx;
            int ii = 0;
            while (b >= 64 - ii) { b -= 64 - ii; ++ii; }
            i = ii; j = ii + b;
            isRead = true;
        }
    } else {
        const int b = (blockIdx.x & 7) * 260 + (blockIdx.x >> 3);
        int jj = (int)((sqrtf(8.0f * (float)b + 1.0f) - 1.0f) * 0.5f);
        while ((jj + 1) * (jj + 2) / 2 <= b) ++jj;
        while (jj * (jj + 1) / 2 > b) --jj;
        i = b - jj * (jj + 1) / 2;
        j = jj;
    }
    const int r0 = i * 128;
    const int c0 = j * 128;
    const bool diag = (i == j);

    if (tid < 128) {
        nAs[tid] = norms[r0 + tid];
        nBs[tid] = norms[c0 + tid];
        const float ta = tauB[r0 + tid];
        const float tb = tauB[c0 + tid];
        tA[tid] = ta;
        tB[tid] = tb;
        tAh[tid] = tau_h_up(ta);
        tBh[tid] = tau_h_up(tb);
        cntR[tid] = 0;
        cntC[tid] = 0;
    }

    if (SUBT > 0 && isRead) {
        // ---- read-tile: u16 bit-compare against fp16-up taus, all-register ----
        __syncthreads();
        const int cc   = tid >> 1;
        const int half = tid & 1;
        const u16 tbh = tBh[cc];
        const us8* src  = (const us8*)(d2h + (size_t)(c0 + cc) * 1024 + r0 + half * 64);
        const us8* tsrc = (const us8*)&tAh[half * 64];
#pragma unroll
        for (int q = 0; q < 8; ++q) {
            const us8 v  = src[q];
            const us8 tq = tsrc[q];
#pragma unroll
            for (int k = 0; k < 8; ++k) {
                const u16 val16 = (u16)v[k];
                if (val16 < (u16)tq[k]) {             // row-side
                    const int rloc = half * 64 + q * 8 + k;
                    const float val = (float)__builtin_bit_cast(_Float16, val16);
                    const int idx2 = atomicAdd(&cntR[rloc], 1);
                    if (idx2 < CAPL) candR[rloc * CAPL + idx2] = val;
                    else {
                        const int g = atomicAdd(&cnt_g[r0 + rloc], 1);
                        if (g < CAPG) cand_g[(size_t)(r0 + rloc) * CAPG + g] = val;
                    }
                }
                if (!diag && val16 < tbh) {           // col-side
                    const float val = (float)__builtin_bit_cast(_Float16, val16);
                    const int idx2 = atomicAdd(&cntC[cc], 1);
                    if (idx2 < CAPL) candC[cc * CAPL + idx2] = val;
                    else {
                        const int g = atomicAdd(&cnt_g[c0 + cc], 1);
                        if (g < CAPG) cand_g[(size_t)(c0 + cc) * CAPG + g] = val;
                    }
                }
            }
        }
    } else {
        // ---- compute path (R6-proven) ----
        const int rb  = tid >> 3;
        const int chS = (tid & 7) ^ ((tid >> 3) & 7);
        const int lofs = tid * 8;

        f32x4 acc[4][4];
#pragma unroll
        for (int m = 0; m < 4; ++m)
#pragma unroll
            for (int n = 0; n < 4; ++n) {
                f32x4 z = {0.f, 0.f, 0.f, 0.f};
                acc[m][n] = z;
            }

        for (int ks = 0; ks < KSTEPS; ++ks) {
            const int kofs = ks * 64 + chS * 8;
#pragma unroll
            for (int it = 0; it < 4; ++it) {
                const int r = it * 32 + rb;
                gload16(Xh + (size_t)(r0 + r) * D_DIM + kofs, &As[it * 2048 + lofs]);
                gload16(Xh + (size_t)(c0 + r) * D_DIM + kofs, &Bs[it * 2048 + lofs]);
            }
            __syncthreads();
#pragma unroll
            for (int kk = 0; kk < 2; ++kk) {
                half8 af[4], bf[4];
#pragma unroll
                for (int m = 0; m < 4; ++m) {
                    const int ra = wr * 64 + m * 16 + l15;
                    const int ch = (kk * 4 + l16) ^ (ra & 7);
                    af[m] = *reinterpret_cast<const half8*>(&As[ra * 64 + ch * 8]);
                }
#pragma unroll
                for (int n = 0; n < 4; ++n) {
                    const int rc = wc * 64 + n * 16 + l15;
                    const int ch = (kk * 4 + l16) ^ (rc & 7);
                    bf[n] = *reinterpret_cast<const half8*>(&Bs[rc * 64 + ch * 8]);
                }
#pragma unroll
                for (int m = 0; m < 4; ++m)
#pragma unroll
                    for (int n = 0; n < 4; ++n)
                        acc[m][n] = __builtin_amdgcn_mfma_f32_16x16x32_f16(af[m], bf[n], acc[m][n], 0, 0, 0);
            }
            __syncthreads();
        }

        float nBc[4], tBc[4];
#pragma unroll
        for (int n = 0; n < 4; ++n) {
            const int ci = wc * 64 + n * 16 + l15;
            nBc[n] = nBs[ci];
            tBc[n] = tB[ci];
        }

#pragma unroll
        for (int m = 0; m < 4; ++m)
#pragma unroll
            for (int r = 0; r < 4; ++r) {
                const int ri = wr * 64 + m * 16 + l16 * 4 + r;
                const float na = nAs[ri];
                const float ta = tA[ri];
#pragma unroll
                for (int n = 0; n < 4; ++n) {
                    const float val = na + nBc[n] - 2.0f * acc[m][n][r];
                    if (val < ta) {                      // row-side
                        const int idx2 = atomicAdd(&cntR[ri], 1);
                        if (idx2 < CAPL) candR[ri * CAPL + idx2] = val;
                        else {
                            const int g = atomicAdd(&cnt_g[r0 + ri], 1);
                            if (g < CAPG) cand_g[(size_t)(r0 + ri) * CAPG + g] = val;
                        }
                    }
                    if (!diag && val < tBc[n]) {         // col-side (symmetry)
                        const int ci = wc * 64 + n * 16 + l15;
                        const int idx2 = atomicAdd(&cntC[ci], 1);
                        if (idx2 < CAPL) candC[ci * CAPL + idx2] = val;
                        else {
                            const int g = atomicAdd(&cnt_g[c0 + ci], 1);
                            if (g < CAPG) cand_g[(size_t)(c0 + ci) * CAPG + g] = val;
                        }
                    }
                }
            }
    }

    __syncthreads();
    if (tid < 128) {
        {   // row-side writeout
            const int row = r0 + tid;
            const int c = (cntR[tid] < CAPL) ? cntR[tid] : CAPL;
            if (c > 0) {
                const int base = atomicAdd(&cnt_g[row], c);
                for (int qq = 0; qq < c; ++qq) {
                    const int s = base + qq;
                    if (s < CAPG) cand_g[(size_t)row * CAPG + s] = candR[tid * CAPL + qq];
                }
            }
        }
        if (!diag) {   // col-side writeout
            const int row = c0 + tid;
            const int c = (cntC[tid] < CAPL) ? cntC[tid] : CAPL;
            if (c > 0) {
                const int base = atomicAdd(&cnt_g[row], c);
                for (int qq = 0; qq < c; ++qq) {
                    const int s = base + qq;
                    if (s < CAPG) cand_g[(size_t)row * CAPG + s] = candC[tid * CAPL + qq];
                }
            }
        }
    }
}

// ---------------- kernel 5: per-row top-21 stats + LID ----
__global__ __launch_bounds__(256) void finalize_kernel(const float* __restrict__ cand_g,
                                                       const int* __restrict__ cnt_g,
                                                       float* __restrict__ out) {
    const int tid  = threadIdx.x;
    const int lane = tid & 63;
    const int row  = blockIdx.x * 4 + (tid >> 6);

    int cnt = cnt_g[row];
    if (cnt > CAPG) cnt = CAPG;
    const float INFV = __uint_as_float(0x7F800000u);

    float v[7];
    unsigned b[7];
#pragma unroll
    for (int j = 0; j < 7; ++j) {
        const int s = lane + 64 * j;
        v[j] = (s < cnt) ? fmaxf(cand_g[(size_t)row * CAPG + s], 0.0f) : INFV;
        b[j] = __float_as_uint(v[j]);
    }

    unsigned lo = 0, hi = 0x7F7FFFFFu;
#pragma unroll
    for (int it = 0; it < 31; ++it) {
        const unsigned mid = (lo + hi) >> 1;
        int c = 0;
#pragma unroll
        for (int j = 0; j < 7; ++j) c += (b[j] <= mid);
        c = wred_sum_i(c);
        if (c >= TOPK) hi = mid; else lo = mid + 1;
    }
    const float th = __uint_as_float(lo);

    int clt = 0;
    float slt = 0.f, mn = INFV;
#pragma unroll
    for (int j = 0; j < 7; ++j) {
        if (b[j] < lo) {
            clt += 1;
            slt += sqrtf(fmaxf(v[j], 1e-12f));
        }
        mn = fminf(mn, v[j]);
    }
    clt = wred_sum_i(clt);
    slt = wred_sum_f(slt);
    mn  = wred_min_f(mn);

    if (lane == 0) {
        const float a20 = sqrtf(fmaxf(th, 1e-12f));
        const float a0  = sqrtf(fmaxf(mn, 1e-12f));
        const float S21 = slt + (float)(TOPK - clt) * a20;
        const float m   = (S21 - a0 - a20) * (1.0f / 19.0f);
        const float lid = m / (a20 - m);
        out[row] = -fabsf(logf(lid));
    }
}

extern "C" void kernel_launch(void* const* d_in, const int* in_sizes, int n_in,
                              void* d_out, int out_size, void* d_ws, size_t ws_size,
                              hipStream_t stream) {
    const float* X = (const float*)d_in[0];
    float* out = (float*)d_out;
    char* ws = (char*)d_ws;

    u16*   Xh    = (u16*)ws;                      // 12,582,912 B
    float* norms = (float*)(ws + 12582912);       //     32,768 B
    float* tauB  = (float*)(ws + 12615680);       //     32,768 B
    int*   cnt_g = (int*)(ws + 12648448);         //     32,768 B
    u16*   d2h   = (u16*)(ws + 12681216);         // 16,777,216 B (8192x1024 fp16)

    // Layout A (ws >= 44.14 MB): cand_g separate -> filter read-tiles for i<8.
    // Layout B: cand_g aliases d2h -> all-compute triangle (R6-exact).
    const bool bigws = (ws_size >= (size_t)44138496);
    float* cand_g = bigws ? (float*)(ws + 29458432) : (float*)(ws + 12681216);

    prep_kernel<<<N_PTS / 4, 256, 0, stream>>>(X, Xh, norms, cnt_g);
    gemm_tau_kernel<<<512, 256, 0, stream>>>(Xh, norms, d2h);
    tau_select_kernel<<<N_PTS / 4, 256, 0, stream>>>(d2h, tauB);
    if (bigws)
        gemm_filter_sym<8><<<2080, 256, 0, stream>>>(Xh, norms, tauB, d2h, cand_g, cnt_g);
    else
        gemm_filter_sym<0><<<2080, 256, 0, stream>>>(Xh, norms, tauB, d2h, cand_g, cnt_g);
    finalize_kernel<<<N_PTS / 4, 256, 0, stream>>>(cand_g, cnt_g, out);
}

// Round 14
// 125.536 us; speedup vs baseline: 1.6603x; 1.1809x over previous
//
#include <hip/hip_runtime.h>
#include <hip/hip_fp16.h>

typedef unsigned short u16;
using f32x4 = __attribute__((ext_vector_type(4))) float;
using half8 = __attribute__((ext_vector_type(8))) _Float16;
using us4   = __attribute__((ext_vector_type(4))) unsigned short;

#define N_PTS 8192
#define D_DIM 768
#define TOPK  21
#define KSTEPS 12
#define CAPL  8
#define CAPG  448
// Analytic threshold offset: tau(i) = norm(i) + TAU_C.
// d2(i,j)|i = n_i + (n_j - 2 x_i.x_j); bracket ~ mean 768, sigma 67.9.
// TAU_C = 768 - 1.96*67.9 ~= 635 -> E[cand/row] ~= 205; P(miss) ~ 1e-50.
// Correctness for ANY input is guaranteed by rescue_kernel (exact fallback).
#define TAU_C 635.0f

// ---------------- async global->LDS (16B per lane) ----------------
__device__ __forceinline__ void gload16(const void* g, void* l) {
    __builtin_amdgcn_global_load_lds(
        (const __attribute__((address_space(1))) void*)g,
        (__attribute__((address_space(3))) void*)l,
        16, 0, 0);
}

// ---------------- wave (64-lane) reductions ----------------
__device__ __forceinline__ int wred_sum_i(int c) {
#pragma unroll
    for (int o = 32; o >= 1; o >>= 1) c += __shfl_xor(c, o, 64);
    return c;
}
__device__ __forceinline__ float wred_sum_f(float c) {
#pragma unroll
    for (int o = 32; o >= 1; o >>= 1) c += __shfl_xor(c, o, 64);
    return c;
}
__device__ __forceinline__ float wred_min_f(float c) {
#pragma unroll
    for (int o = 32; o >= 1; o >>= 1) c = fminf(c, __shfl_xor(c, o, 64));
    return c;
}

// branch-free sorted top-k insert (ascending), used by rescue only
__device__ __forceinline__ void topk_insert(float (&t)[TOPK], float x) {
    if (x >= t[TOPK - 1]) return;
#pragma unroll
    for (int i = TOPK - 1; i >= 1; --i) {
        float tp = t[i - 1];
        t[i] = (x < tp) ? tp : fminf(x, t[i]);
    }
    t[0] = fminf(t[0], x);
}

// ---------------- kernel 1: fp32 -> fp16 + row norms (vectorized) ----
__global__ __launch_bounds__(256) void prep_kernel(const float* __restrict__ X,
                                                   u16* __restrict__ Xh,
                                                   float* __restrict__ norms,
                                                   int* __restrict__ cnt_g) {
    const int tid  = threadIdx.x;
    const int lane = tid & 63;
    const int row  = blockIdx.x * 4 + (tid >> 6);
    const float4* xr = (const float4*)(X + (size_t)row * D_DIM);
    us4* hr = (us4*)(Xh + (size_t)row * D_DIM);
    float s = 0.f;
#pragma unroll
    for (int j = 0; j < 3; ++j) {
        const float4 v = xr[lane + j * 64];
        _Float16 h0 = (_Float16)v.x, h1 = (_Float16)v.y,
                 h2 = (_Float16)v.z, h3 = (_Float16)v.w;
        us4 u;
        u[0] = __builtin_bit_cast(u16, h0);
        u[1] = __builtin_bit_cast(u16, h1);
        u[2] = __builtin_bit_cast(u16, h2);
        u[3] = __builtin_bit_cast(u16, h3);
        hr[lane + j * 64] = u;
        const float f0 = (float)h0, f1 = (float)h1, f2 = (float)h2, f3 = (float)h3;
        s += f0 * f0 + f1 * f1 + f2 * f2 + f3 * f3;
    }
#pragma unroll
    for (int o = 32; o >= 1; o >>= 1) s += __shfl_down(s, o, 64);
    if (lane == 0) {
        norms[row] = s;
        cnt_g[row] = 0;
    }
}

// ---------------- kernel 2: SYMMETRIC upper-triangle GEMM + two-sided filter ----
// 2080 = 64*65/2 tiles of 128x128 (i<=j). R6-measured config (92.3 us).
// tau(i) = norms[i] + TAU_C computed in-kernel; no strip, no tau arrays in global.
__global__ __launch_bounds__(256, 3) void gemm_filter_sym(const u16* __restrict__ Xh,
                                                          const float* __restrict__ norms,
                                                          float* __restrict__ cand_g,
                                                          int* __restrict__ cnt_g) {
    __shared__ __align__(16) u16 As[128 * 64];       // 16384 B
    __shared__ __align__(16) u16 Bs[128 * 64];       // 16384 B
    __shared__ float candR[128 * CAPL];              //  4096 B
    __shared__ float candC[128 * CAPL];              //  4096 B
    __shared__ int   cntR[128];
    __shared__ int   cntC[128];
    __shared__ float nAs[128], nBs[128], tA[128], tB[128];

    const int tid  = threadIdx.x;
    const int lane = tid & 63;
    const int wid  = tid >> 6;
    const int wr   = wid >> 1;
    const int wc   = wid & 1;
    const int l16  = lane >> 4;
    const int l15  = lane & 15;

    // XCD swizzle (2080 = 8 * 260) then triangular decode: b = j*(j+1)/2 + i, i<=j
    const int b = (blockIdx.x & 7) * 260 + (blockIdx.x >> 3);
    int j = (int)((sqrtf(8.0f * (float)b + 1.0f) - 1.0f) * 0.5f);
    while ((j + 1) * (j + 2) / 2 <= b) ++j;
    while (j * (j + 1) / 2 > b) --j;
    const int i = b - j * (j + 1) / 2;
    const int r0 = i * 128;
    const int c0 = j * 128;
    const bool diag = (i == j);

    if (tid < 128) {
        const float na = norms[r0 + tid];
        const float nb = norms[c0 + tid];
        nAs[tid] = na;
        nBs[tid] = nb;
        tA[tid]  = na + TAU_C;
        tB[tid]  = nb + TAU_C;
        cntR[tid] = 0;
        cntC[tid] = 0;
    }

    // staging geometry: 8 lanes per 128B row; T2 source-side XOR swizzle
    const int rb  = tid >> 3;
    const int chS = (tid & 7) ^ ((tid >> 3) & 7);
    const int lofs = tid * 8;

    f32x4 acc[4][4];
#pragma unroll
    for (int m = 0; m < 4; ++m)
#pragma unroll
        for (int n = 0; n < 4; ++n) {
            f32x4 z = {0.f, 0.f, 0.f, 0.f};
            acc[m][n] = z;
        }

    for (int ks = 0; ks < KSTEPS; ++ks) {
        const int kofs = ks * 64 + chS * 8;
#pragma unroll
        for (int it = 0; it < 4; ++it) {
            const int r = it * 32 + rb;
            gload16(Xh + (size_t)(r0 + r) * D_DIM + kofs, &As[it * 2048 + lofs]);
            gload16(Xh + (size_t)(c0 + r) * D_DIM + kofs, &Bs[it * 2048 + lofs]);
        }
        __syncthreads();
#pragma unroll
        for (int kk = 0; kk < 2; ++kk) {
            half8 af[4], bf[4];
#pragma unroll
            for (int m = 0; m < 4; ++m) {
                const int ra = wr * 64 + m * 16 + l15;
                const int ch = (kk * 4 + l16) ^ (ra & 7);
                af[m] = *reinterpret_cast<const half8*>(&As[ra * 64 + ch * 8]);
            }
#pragma unroll
            for (int n = 0; n < 4; ++n) {
                const int rc = wc * 64 + n * 16 + l15;
                const int ch = (kk * 4 + l16) ^ (rc & 7);
                bf[n] = *reinterpret_cast<const half8*>(&Bs[rc * 64 + ch * 8]);
            }
#pragma unroll
            for (int m = 0; m < 4; ++m)
#pragma unroll
                for (int n = 0; n < 4; ++n)
                    acc[m][n] = __builtin_amdgcn_mfma_f32_16x16x32_f16(af[m], bf[n], acc[m][n], 0, 0, 0);
        }
        __syncthreads();
    }

    // ---- two-sided filter epilogue ----
    float nBc[4], tBc[4];
#pragma unroll
    for (int n = 0; n < 4; ++n) {
        const int ci = wc * 64 + n * 16 + l15;
        nBc[n] = nBs[ci];
        tBc[n] = tB[ci];
    }

#pragma unroll
    for (int m = 0; m < 4; ++m)
#pragma unroll
        for (int r = 0; r < 4; ++r) {
            const int ri = wr * 64 + m * 16 + l16 * 4 + r;
            const float na = nAs[ri];
            const float ta = tA[ri];
#pragma unroll
            for (int n = 0; n < 4; ++n) {
                const float val = na + nBc[n] - 2.0f * acc[m][n][r];
                if (val < ta) {                      // row-side candidate
                    const int idx2 = atomicAdd(&cntR[ri], 1);
                    if (idx2 < CAPL) candR[ri * CAPL + idx2] = val;
                    else {
                        const int g = atomicAdd(&cnt_g[r0 + ri], 1);
                        if (g < CAPG) cand_g[(size_t)(r0 + ri) * CAPG + g] = val;
                    }
                }
                if (!diag && val < tBc[n]) {         // col-side candidate (symmetry)
                    const int ci = wc * 64 + n * 16 + l15;
                    const int idx2 = atomicAdd(&cntC[ci], 1);
                    if (idx2 < CAPL) candC[ci * CAPL + idx2] = val;
                    else {
                        const int g = atomicAdd(&cnt_g[c0 + ci], 1);
                        if (g < CAPG) cand_g[(size_t)(c0 + ci) * CAPG + g] = val;
                    }
                }
            }
        }

    __syncthreads();
    if (tid < 128) {
        {   // row-side writeout
            const int row = r0 + tid;
            const int c = (cntR[tid] < CAPL) ? cntR[tid] : CAPL;
            if (c > 0) {
                const int base = atomicAdd(&cnt_g[row], c);
                for (int q = 0; q < c; ++q) {
                    const int s = base + q;
                    if (s < CAPG) cand_g[(size_t)row * CAPG + s] = candR[tid * CAPL + q];
                }
            }
        }
        if (!diag) {   // col-side writeout
            const int row = c0 + tid;
            const int c = (cntC[tid] < CAPL) ? cntC[tid] : CAPL;
            if (c > 0) {
                const int base = atomicAdd(&cnt_g[row], c);
                for (int q = 0; q < c; ++q) {
                    const int s = base + q;
                    if (s < CAPG) cand_g[(size_t)row * CAPG + s] = candC[tid * CAPL + q];
                }
            }
        }
    }
}

// ---------------- kernel 3: rescue net (exact fallback; executes never in practice) ----
// Any row with cnt<TOPK (threshold too tight) or cnt>CAPG (slots overflowed)
// gets an exact wave-parallel brute-force top-21 rewritten into cand_g.
__global__ __launch_bounds__(256) void rescue_kernel(const u16* __restrict__ Xh,
                                                     const float* __restrict__ norms,
                                                     float* __restrict__ cand_g,
                                                     int* __restrict__ cnt_g) {
    const int tid  = threadIdx.x;
    const int lane = tid & 63;
    const int row  = blockIdx.x * 256 + tid;
    const int cnt  = cnt_g[row];
    const bool bad = (cnt < TOPK) || (cnt > CAPG);

    unsigned long long ballot = __ballot(bad);
    while (ballot) {
        const int l = __ffsll((long long)ballot) - 1;
        ballot &= ballot - 1;
        const int R = __shfl(row, l, 64);

        // exact: each lane scans cols lane, lane+64, ... (128 cols)
        const float nR = norms[R];
        float t[TOPK];
#pragma unroll
        for (int q = 0; q < TOPK; ++q) t[q] = 3e38f;
        for (int c = lane; c < N_PTS; c += 64) {
            const u16* xa = Xh + (size_t)R * D_DIM;
            const u16* xb = Xh + (size_t)c * D_DIM;
            float dot = 0.f;
            for (int d = 0; d < D_DIM; ++d) {
                const float a = (float)__builtin_bit_cast(_Float16, xa[d]);
                const float b = (float)__builtin_bit_cast(_Float16, xb[d]);
                dot += a * b;
            }
            topk_insert(t, fmaxf(nR + norms[c] - 2.0f * dot, 0.0f));
        }
        // wave 21st-smallest via bit search (values >= 0)
        unsigned lo = 0, hi = 0x7F7FFFFFu;
        for (int it = 0; it < 31; ++it) {
            const unsigned mid = (lo + hi) >> 1;
            int c = 0;
#pragma unroll
            for (int q = 0; q < TOPK; ++q) c += (__float_as_uint(t[q]) <= mid);
            c = wred_sum_i(c);
            if (c >= TOPK) hi = mid; else lo = mid + 1;
        }
        if (lane == 0) cnt_g[R] = 0;
#pragma unroll
        for (int q = 0; q < TOPK; ++q) {
            if (__float_as_uint(t[q]) <= lo) {
                const int g = atomicAdd(&cnt_g[R], 1);
                if (g < CAPG) cand_g[(size_t)R * CAPG + g] = t[q];
            }
        }
    }
}

// ---------------- kernel 4: per-row top-21 stats + LID ----
__global__ __launch_bounds__(256) void finalize_kernel(const float* __restrict__ cand_g,
                                                       const int* __restrict__ cnt_g,
                                                       float* __restrict__ out) {
    const int tid  = threadIdx.x;
    const int lane = tid & 63;
    const int row  = blockIdx.x * 4 + (tid >> 6);

    int cnt = cnt_g[row];
    if (cnt > CAPG) cnt = CAPG;
    const float INFV = __uint_as_float(0x7F800000u);

    float v[7];
    unsigned b[7];
#pragma unroll
    for (int j = 0; j < 7; ++j) {
        const int s = lane + 64 * j;
        v[j] = (s < cnt) ? fmaxf(cand_g[(size_t)row * CAPG + s], 0.0f) : INFV;
        b[j] = __float_as_uint(v[j]);
    }

    unsigned lo = 0, hi = 0x7F7FFFFFu;
#pragma unroll
    for (int it = 0; it < 31; ++it) {
        const unsigned mid = (lo + hi) >> 1;
        int c = 0;
#pragma unroll
        for (int j = 0; j < 7; ++j) c += (b[j] <= mid);
        c = wred_sum_i(c);
        if (c >= TOPK) hi = mid; else lo = mid + 1;
    }
    const float th = __uint_as_float(lo);

    int clt = 0;
    float slt = 0.f, mn = INFV;
#pragma unroll
    for (int j = 0; j < 7; ++j) {
        if (b[j] < lo) {
            clt += 1;
            slt += sqrtf(fmaxf(v[j], 1e-12f));
        }
        mn = fminf(mn, v[j]);
    }
    clt = wred_sum_i(clt);
    slt = wred_sum_f(slt);
    mn  = wred_min_f(mn);

    if (lane == 0) {
        const float a20 = sqrtf(fmaxf(th, 1e-12f));
        const float a0  = sqrtf(fmaxf(mn, 1e-12f));
        const float S21 = slt + (float)(TOPK - clt) * a20;
        const float m   = (S21 - a0 - a20) * (1.0f / 19.0f);
        const float lid = m / (a20 - m);
        out[row] = -fabsf(logf(lid));
    }
}

extern "C" void kernel_launch(void* const* d_in, const int* in_sizes, int n_in,
                              void* d_out, int out_size, void* d_ws, size_t ws_size,
                              hipStream_t stream) {
    const float* X = (const float*)d_in[0];
    float* out = (float*)d_out;
    char* ws = (char*)d_ws;

    u16*   Xh     = (u16*)ws;                     // 12,582,912 B
    float* norms  = (float*)(ws + 12582912);      //     32,768 B
    int*   cnt_g  = (int*)(ws + 12615680);        //     32,768 B
    float* cand_g = (float*)(ws + 12648448);      // 14,680,064 B (8192 x 448 f32)
                                                  // total 27,328,512 B

    prep_kernel<<<N_PTS / 4, 256, 0, stream>>>(X, Xh, norms, cnt_g);
    gemm_filter_sym<<<2080, 256, 0, stream>>>(Xh, norms, cand_g, cnt_g);
    rescue_kernel<<<N_PTS / 256, 256, 0, stream>>>(Xh, norms, cand_g, cnt_g);
    finalize_kernel<<<N_PTS / 4, 256, 0, stream>>>(cand_g, cnt_g, out);
}

// Round 15
// 113.459 us; speedup vs baseline: 1.8370x; 1.1064x over previous
//
#include <hip/hip_runtime.h>
#include <hip/hip_fp16.h>

typedef unsigned short u16;
using f32x4 = __attribute__((ext_vector_type(4))) float;
using half8 = __attribute__((ext_vector_type(8))) _Float16;
using us4   = __attribute__((ext_vector_type(4))) unsigned short;

#define N_PTS 8192
#define D_DIM 768
#define TOPK  21
#define KSTEPS 12
#define CAPL  5          // lambda/tile-side ~0.94 -> P(>5) ~3e-4, ~200 spills total
#define CAPG  192        // E[cand/row]=60, +17 sigma
#define ZTAU  2.44f      // tau_i = n_i + 768 - ZTAU*sqrt(1536+4 n_i) -> E=60/row

// ---------------- async global->LDS (16B per lane) ----------------
__device__ __forceinline__ void gload16(const void* g, void* l) {
    __builtin_amdgcn_global_load_lds(
        (const __attribute__((address_space(1))) void*)g,
        (__attribute__((address_space(3))) void*)l,
        16, 0, 0);
}

// ---------------- wave (64-lane) reductions ----------------
__device__ __forceinline__ int wred_sum_i(int c) {
#pragma unroll
    for (int o = 32; o >= 1; o >>= 1) c += __shfl_xor(c, o, 64);
    return c;
}
__device__ __forceinline__ float wred_sum_f(float c) {
#pragma unroll
    for (int o = 32; o >= 1; o >>= 1) c += __shfl_xor(c, o, 64);
    return c;
}
__device__ __forceinline__ float wred_min_f(float c) {
#pragma unroll
    for (int o = 32; o >= 1; o >>= 1) c = fminf(c, __shfl_xor(c, o, 64));
    return c;
}

// branch-free sorted top-k insert (ascending), rescue path only
__device__ __forceinline__ void topk_insert(float (&t)[TOPK], float x) {
    if (x >= t[TOPK - 1]) return;
#pragma unroll
    for (int i = TOPK - 1; i >= 1; --i) {
        float tp = t[i - 1];
        t[i] = (x < tp) ? tp : fminf(x, t[i]);
    }
    t[0] = fminf(t[0], x);
}

// ---------------- kernel 1: fp32 -> fp16 + row norms (vectorized) ----
__global__ __launch_bounds__(256) void prep_kernel(const float* __restrict__ X,
                                                   u16* __restrict__ Xh,
                                                   float* __restrict__ norms,
                                                   int* __restrict__ cnt_g) {
    const int tid  = threadIdx.x;
    const int lane = tid & 63;
    const int row  = blockIdx.x * 4 + (tid >> 6);
    const float4* xr = (const float4*)(X + (size_t)row * D_DIM);
    us4* hr = (us4*)(Xh + (size_t)row * D_DIM);
    float s = 0.f;
#pragma unroll
    for (int j = 0; j < 3; ++j) {
        const float4 v = xr[lane + j * 64];
        _Float16 h0 = (_Float16)v.x, h1 = (_Float16)v.y,
                 h2 = (_Float16)v.z, h3 = (_Float16)v.w;
        us4 u;
        u[0] = __builtin_bit_cast(u16, h0);
        u[1] = __builtin_bit_cast(u16, h1);
        u[2] = __builtin_bit_cast(u16, h2);
        u[3] = __builtin_bit_cast(u16, h3);
        hr[lane + j * 64] = u;
        const float f0 = (float)h0, f1 = (float)h1, f2 = (float)h2, f3 = (float)h3;
        s += f0 * f0 + f1 * f1 + f2 * f2 + f3 * f3;
    }
#pragma unroll
    for (int o = 32; o >= 1; o >>= 1) s += __shfl_down(s, o, 64);
    if (lane == 0) {
        norms[row] = s;
        cnt_g[row] = 0;
    }
}

// ---------------- kernel 2: SYMMETRIC upper-triangle GEMM + two-sided filter ----
// 2080 = 64*65/2 tiles (i<=j). LDS exactly 40960 B -> 4 blocks/CU.
// Per-row tau via hC = 0.5*(768 - Z*sqrt(1536+4n)); compares in acc-domain.
__global__ __launch_bounds__(256, 4) void gemm_filter_sym(const u16* __restrict__ Xh,
                                                          const float* __restrict__ norms,
                                                          float* __restrict__ cand_g,
                                                          int* __restrict__ cnt_g) {
    __shared__ __align__(16) u16 As[128 * 64];       // 16384 B
    __shared__ __align__(16) u16 Bs[128 * 64];       // 16384 B
    __shared__ float candR[128 * CAPL];              //  2560 B
    __shared__ float candC[128 * CAPL];              //  2560 B
    __shared__ int   cntR[128];                      //   512 B
    __shared__ int   cntC[128];                      //   512 B
    __shared__ float hNa[128], hNb[128], hCr[128], hCc[128];  // 2048 B => 40960

    const int tid  = threadIdx.x;
    const int lane = tid & 63;
    const int wid  = tid >> 6;
    const int wr   = wid >> 1;
    const int wc   = wid & 1;
    const int l16  = lane >> 4;
    const int l15  = lane & 15;

    // XCD swizzle (2080 = 8 * 260) then triangular decode: b = j*(j+1)/2 + i, i<=j
    const int b = (blockIdx.x & 7) * 260 + (blockIdx.x >> 3);
    int j = (int)((sqrtf(8.0f * (float)b + 1.0f) - 1.0f) * 0.5f);
    while ((j + 1) * (j + 2) / 2 <= b) ++j;
    while (j * (j + 1) / 2 > b) --j;
    const int i = b - j * (j + 1) / 2;
    const int r0 = i * 128;
    const int c0 = j * 128;
    const bool diag = (i == j);

    if (tid < 128) {
        const float na = norms[r0 + tid];
        const float nb = norms[c0 + tid];
        hNa[tid] = 0.5f * na;
        hNb[tid] = 0.5f * nb;
        hCr[tid] = 0.5f * (768.0f - ZTAU * sqrtf(1536.0f + 4.0f * na));
        hCc[tid] = 0.5f * (768.0f - ZTAU * sqrtf(1536.0f + 4.0f * nb));
        cntR[tid] = 0;
        cntC[tid] = 0;
    }

    // staging geometry: 8 lanes per 128B row; T2 source-side XOR swizzle
    const int rb  = tid >> 3;
    const int chS = (tid & 7) ^ ((tid >> 3) & 7);
    const int lofs = tid * 8;

    f32x4 acc[4][4];
#pragma unroll
    for (int m = 0; m < 4; ++m)
#pragma unroll
        for (int n = 0; n < 4; ++n) {
            f32x4 z = {0.f, 0.f, 0.f, 0.f};
            acc[m][n] = z;
        }

    for (int ks = 0; ks < KSTEPS; ++ks) {
        const int kofs = ks * 64 + chS * 8;
#pragma unroll
        for (int it = 0; it < 4; ++it) {
            const int r = it * 32 + rb;
            gload16(Xh + (size_t)(r0 + r) * D_DIM + kofs, &As[it * 2048 + lofs]);
            gload16(Xh + (size_t)(c0 + r) * D_DIM + kofs, &Bs[it * 2048 + lofs]);
        }
        __syncthreads();
#pragma unroll
        for (int kk = 0; kk < 2; ++kk) {
            half8 af[4], bf[4];
#pragma unroll
            for (int m = 0; m < 4; ++m) {
                const int ra = wr * 64 + m * 16 + l15;
                const int ch = (kk * 4 + l16) ^ (ra & 7);
                af[m] = *reinterpret_cast<const half8*>(&As[ra * 64 + ch * 8]);
            }
#pragma unroll
            for (int n = 0; n < 4; ++n) {
                const int rc = wc * 64 + n * 16 + l15;
                const int ch = (kk * 4 + l16) ^ (rc & 7);
                bf[n] = *reinterpret_cast<const half8*>(&Bs[rc * 64 + ch * 8]);
            }
#pragma unroll
            for (int m = 0; m < 4; ++m)
#pragma unroll
                for (int n = 0; n < 4; ++n)
                    acc[m][n] = __builtin_amdgcn_mfma_f32_16x16x32_f16(af[m], bf[n], acc[m][n], 0, 0, 0);
        }
        __syncthreads();
    }

    // ---- two-sided filter epilogue, acc-domain compares ----
    float hNb_n[4], hCc_n[4];
#pragma unroll
    for (int n = 0; n < 4; ++n) {
        const int ci = wc * 64 + n * 16 + l15;
        hNb_n[n] = hNb[ci];
        hCc_n[n] = hCc[ci];
    }

#pragma unroll
    for (int m = 0; m < 4; ++m)
#pragma unroll
        for (int r = 0; r < 4; ++r) {
            const int ri = wr * 64 + m * 16 + l16 * 4 + r;
            const float hna = hNa[ri];
            const float hcr = hCr[ri];
#pragma unroll
            for (int n = 0; n < 4; ++n) {
                const float d = acc[m][n][r];
                // rowHit: d2 < tau_row  <=>  acc > 0.5*nB - 0.5*C_row
                if (d > hNb_n[n] - hcr) {
                    const float val = 2.0f * (hna + hNb_n[n] - d);
                    const int idx2 = atomicAdd(&cntR[ri], 1);
                    if (idx2 < CAPL) candR[ri * CAPL + idx2] = val;
                    else {
                        const int g = atomicAdd(&cnt_g[r0 + ri], 1);
                        if (g < CAPG) cand_g[(size_t)(r0 + ri) * CAPG + g] = val;
                    }
                }
                // colHit: d2 < tau_col  <=>  acc > 0.5*nA - 0.5*C_col
                if (!diag && d > hna - hCc_n[n]) {
                    const int ci = wc * 64 + n * 16 + l15;
                    const float val = 2.0f * (hna + hNb_n[n] - d);
                    const int idx2 = atomicAdd(&cntC[ci], 1);
                    if (idx2 < CAPL) candC[ci * CAPL + idx2] = val;
                    else {
                        const int g = atomicAdd(&cnt_g[c0 + ci], 1);
                        if (g < CAPG) cand_g[(size_t)(c0 + ci) * CAPG + g] = val;
                    }
                }
            }
        }

    __syncthreads();
    if (tid < 128) {
        {   // row-side writeout
            const int row = r0 + tid;
            const int c = (cntR[tid] < CAPL) ? cntR[tid] : CAPL;
            if (c > 0) {
                const int base = atomicAdd(&cnt_g[row], c);
                for (int q = 0; q < c; ++q) {
                    const int s = base + q;
                    if (s < CAPG) cand_g[(size_t)row * CAPG + s] = candR[tid * CAPL + q];
                }
            }
        }
        if (!diag) {   // col-side writeout
            const int row = c0 + tid;
            const int c = (cntC[tid] < CAPL) ? cntC[tid] : CAPL;
            if (c > 0) {
                const int base = atomicAdd(&cnt_g[row], c);
                for (int q = 0; q < c; ++q) {
                    const int s = base + q;
                    if (s < CAPG) cand_g[(size_t)row * CAPG + s] = candC[tid * CAPL + q];
                }
            }
        }
    }
}

// ---------------- kernel 3: finalize + fused exact rescue ----
// One wave per row. If cnt<21 or cnt>CAPG (never in practice), the wave
// brute-forces the exact top-21; else normal candidate-stats path.
__global__ __launch_bounds__(256) void finalize_kernel(const float* __restrict__ cand_g,
                                                       const int* __restrict__ cnt_g,
                                                       const u16* __restrict__ Xh,
                                                       const float* __restrict__ norms,
                                                       float* __restrict__ out) {
    const int tid  = threadIdx.x;
    const int lane = tid & 63;
    const int row  = blockIdx.x * 4 + (tid >> 6);

    int cnt = cnt_g[row];
    const bool bad = (cnt < TOPK) || (cnt > CAPG);   // wave-uniform
    const float INFV = __uint_as_float(0x7F800000u);

    float a0v, a20v, S21v;
    if (bad) {
        // ---- exact rescue: lane scans cols lane, lane+64, ... ----
        const float nR = norms[row];
        float t[TOPK];
#pragma unroll
        for (int q = 0; q < TOPK; ++q) t[q] = 3e38f;
        for (int c = lane; c < N_PTS; c += 64) {
            const u16* xa = Xh + (size_t)row * D_DIM;
            const u16* xb = Xh + (size_t)c * D_DIM;
            float dot = 0.f;
            for (int d = 0; d < D_DIM; ++d) {
                const float a = (float)__builtin_bit_cast(_Float16, xa[d]);
                const float b = (float)__builtin_bit_cast(_Float16, xb[d]);
                dot += a * b;
            }
            topk_insert(t, fmaxf(nR + norms[c] - 2.0f * dot, 0.0f));
        }
        unsigned lo = 0, hi = 0x7F7FFFFFu;
        for (int it = 0; it < 31; ++it) {
            const unsigned mid = (lo + hi) >> 1;
            int c = 0;
#pragma unroll
            for (int q = 0; q < TOPK; ++q) c += (__float_as_uint(t[q]) <= mid);
            c = wred_sum_i(c);
            if (c >= TOPK) hi = mid; else lo = mid + 1;
        }
        int clt = 0;
        float slt = 0.f, mn = INFV;
#pragma unroll
        for (int q = 0; q < TOPK; ++q) {
            if (__float_as_uint(t[q]) < lo) {
                clt += 1;
                slt += sqrtf(fmaxf(t[q], 1e-12f));
            }
            mn = fminf(mn, t[q]);
        }
        clt = wred_sum_i(clt);
        slt = wred_sum_f(slt);
        mn  = wred_min_f(mn);
        a20v = sqrtf(fmaxf(__uint_as_float(lo), 1e-12f));
        a0v  = sqrtf(fmaxf(mn, 1e-12f));
        S21v = slt + (float)(TOPK - clt) * a20v;
    } else {
        float v[3];
        unsigned bb[3];
#pragma unroll
        for (int j = 0; j < 3; ++j) {
            const int s = lane + 64 * j;
            v[j] = (s < cnt) ? fmaxf(cand_g[(size_t)row * CAPG + s], 0.0f) : INFV;
            bb[j] = __float_as_uint(v[j]);
        }
        unsigned lo = 0, hi = 0x7F7FFFFFu;
#pragma unroll
        for (int it = 0; it < 31; ++it) {
            const unsigned mid = (lo + hi) >> 1;
            int c = 0;
#pragma unroll
            for (int j = 0; j < 3; ++j) c += (bb[j] <= mid);
            c = wred_sum_i(c);
            if (c >= TOPK) hi = mid; else lo = mid + 1;
        }
        int clt = 0;
        float slt = 0.f, mn = INFV;
#pragma unroll
        for (int j = 0; j < 3; ++j) {
            if (bb[j] < lo) {
                clt += 1;
                slt += sqrtf(fmaxf(v[j], 1e-12f));
            }
            mn = fminf(mn, v[j]);
        }
        clt = wred_sum_i(clt);
        slt = wred_sum_f(slt);
        mn  = wred_min_f(mn);
        a20v = sqrtf(fmaxf(__uint_as_float(lo), 1e-12f));
        a0v  = sqrtf(fmaxf(mn, 1e-12f));
        S21v = slt + (float)(TOPK - clt) * a20v;
    }

    if (lane == 0) {
        const float m   = (S21v - a0v - a20v) * (1.0f / 19.0f);
        const float lid = m / (a20v - m);
        out[row] = -fabsf(logf(lid));
    }
}

extern "C" void kernel_launch(void* const* d_in, const int* in_sizes, int n_in,
                              void* d_out, int out_size, void* d_ws, size_t ws_size,
                              hipStream_t stream) {
    const float* X = (const float*)d_in[0];
    float* out = (float*)d_out;
    char* ws = (char*)d_ws;

    u16*   Xh     = (u16*)ws;                     // 12,582,912 B
    float* norms  = (float*)(ws + 12582912);      //     32,768 B
    int*   cnt_g  = (int*)(ws + 12615680);        //     32,768 B
    float* cand_g = (float*)(ws + 12648448);      //  6,291,456 B (8192 x 192 f32)
                                                  // total 18,939,904 B

    prep_kernel<<<N_PTS / 4, 256, 0, stream>>>(X, Xh, norms, cnt_g);
    gemm_filter_sym<<<2080, 256, 0, stream>>>(Xh, norms, cand_g, cnt_g);
    finalize_kernel<<<N_PTS / 4, 256, 0, stream>>>(cand_g, cnt_g, Xh, norms, out);
}